// Round 9
// baseline (394.507 us; speedup 1.0000x reference)
//
#include <hip/hip_runtime.h>
#include <cmath>

#define TABLE_NUM 16
#define T_SIZE    4096
#define Z_DIM     512
#define IMG       256
#define D_TAB     (TABLE_NUM * T_SIZE * 2)       // 131072
#define BATCH     8
#define HID       64
#define N_PIX     (IMG * IMG)                    // 65536
#define PRIME_Y   2654435761u
#define KCHUNK    4
#define KLEN      (Z_DIM / KCHUNK)               // 128
#define NG4       (D_TAB / 4)                    // 32768 float4 col-groups
#define REPS      4                              // measurement repeat factor

typedef _Float16 v8h  __attribute__((ext_vector_type(8)));
typedef _Float16 v2h  __attribute__((ext_vector_type(2)));
typedef float    v4f  __attribute__((ext_vector_type(4)));

struct ResArr { float r[TABLE_NUM]; };

__device__ constexpr int WCAP[16]  = {3,4,4,4,5,5,5,6,7,8,9,10,11,13,15,18};
__device__ constexpr int CBASE[16] = {0,9,25,41,57,82,107,132,168,217,281,362,462,583,752,977};
#define CTOT 1301

// ---------------------------------------------------------------------------
// MEASUREMENT ROUND: R8 source, but gen_partial and hash_mlp repeat their
// (idempotent) bodies 4x inside one dispatch -> both exceed the ~150 us
// poison-fill cutoff and surface in rocprof top-5 with full counters.
// Per-kernel dur = dispatch_dur / 4.
// ---------------------------------------------------------------------------

__global__ void prep_weights(const float* __restrict__ w1, const float* __restrict__ w2,
                             const float* __restrict__ w3, const float* __restrict__ z,
                             _Float16* __restrict__ w1T, _Float16* __restrict__ w2T,
                             _Float16* __restrict__ w3T, float* __restrict__ zT)
{
    const int t = threadIdx.x;
    for (int i = t; i < HID * 32; i += 256) {
        int n = i >> 5, k = i & 31;
        w1T[i] = (_Float16)w1[k * HID + n];
    }
    for (int i = t; i < HID * HID; i += 256) {
        int n = i >> 6, k = i & 63;
        w2T[i] = (_Float16)w2[k * HID + n];
    }
    for (int i = t; i < 16 * HID; i += 256) {
        int n = i >> 6, k = i & 63;
        w3T[i] = (_Float16)(n < 3 ? w3[k * 3 + n] : 0.f);
    }
    for (int i = t; i < Z_DIM * BATCH; i += 256) {
        int k = i >> 3, b = i & 7;
        zT[i] = z[b * Z_DIM + k];
    }
}

__global__ __launch_bounds__(256) void gen_partial(
    const float* __restrict__ zT, const float* __restrict__ w,
    float* __restrict__ part)
{
    const int c  = blockIdx.x >> 7;
    const int g  = (blockIdx.x & 127) * 256 + threadIdx.x;
    const int k0 = c * KLEN;
    const float4* wp = reinterpret_cast<const float4*>(w) + g;

#pragma unroll 1
    for (int rep = 0; rep < REPS; ++rep) {
        float4 acc[BATCH];
#pragma unroll
        for (int b = 0; b < BATCH; ++b) acc[b] = make_float4(0.f, 0.f, 0.f, 0.f);

#pragma unroll 8
        for (int kk = 0; kk < KLEN; ++kk) {
            const int k = k0 + kk;
            float4 wv = wp[(size_t)k * NG4];
            const float* zr = zT + k * BATCH;
#pragma unroll
            for (int b = 0; b < BATCH; ++b) {
                float zv = zr[b];
                acc[b].x = fmaf(zv, wv.x, acc[b].x);
                acc[b].y = fmaf(zv, wv.y, acc[b].y);
                acc[b].z = fmaf(zv, wv.z, acc[b].z);
                acc[b].w = fmaf(zv, wv.w, acc[b].w);
            }
        }

        float4* pp = reinterpret_cast<float4*>(part);
#pragma unroll
        for (int b = 0; b < BATCH; ++b)
            pp[((size_t)(c * BATCH + b) << 15) + g] = acc[b];
    }
}

__global__ __launch_bounds__(256) void gen_reduce(
    const float* __restrict__ part, const float* __restrict__ bt,
    float* __restrict__ tabs)
{
    const int i = blockIdx.x * 256 + threadIdx.x;
    const int b = i >> 15, g = i & (NG4 - 1);
    const float4* pp = reinterpret_cast<const float4*>(part);

    float4 s = pp[((size_t)b << 15) + g];
#pragma unroll
    for (int c = 1; c < KCHUNK; ++c) {
        float4 p = pp[((size_t)(c * BATCH + b) << 15) + g];
        s.x += p.x; s.y += p.y; s.z += p.z; s.w += p.w;
    }
    float4 bv = reinterpret_cast<const float4*>(bt)[g];
    s.x += bv.x; s.y += bv.y; s.z += bv.z; s.w += bv.w;
    reinterpret_cast<float4*>(tabs)[((size_t)b << 15) + g] = s;
}

__global__ __launch_bounds__(256) void hash_mlp(
    const float* __restrict__ tabs,
    const _Float16* __restrict__ w1T, const _Float16* __restrict__ w2T,
    const _Float16* __restrict__ w3T,
    const float* __restrict__ b1, const float* __restrict__ b2,
    const float* __restrict__ b3,
    float* __restrict__ out, ResArr res)
{
    __shared__ _Float16 mbuf[4][64][72];
    __shared__ float2   cstage[CTOT];

    const int tid  = threadIdx.x;
    const int wid  = tid >> 6;
    const int lane = tid & 63;
    const int b    = blockIdx.x & 7;
    const int tile = blockIdx.x >> 3;
    const int i0b  = (tile >> 4) * 16;
    const int j0b  = (tile & 15) * 16;
    const int i0   = i0b + wid * 4;

    const int di = lane >> 4, dj = lane & 15;
    const float cxp = ((float)(i0 + di) + 0.5f) * (1.0f / IMG);
    const float cyp = ((float)(j0b + dj) + 0.5f) * (1.0f / IMG);
    const float2* tb2 = reinterpret_cast<const float2*>(tabs + (size_t)b * D_TAB);

    const float cx_lo = ((float)i0b + 0.5f) * (1.0f / IMG);
    const float cy_lo = ((float)j0b + 0.5f) * (1.0f / IMG);

    const int arow = lane & 15;
    const int kgrp = lane >> 4;

#pragma unroll 1
    for (int rep = 0; rep < REPS; ++rep) {

        // ---- stage the full corner pyramid ----
#pragma unroll
        for (int l = 0; l < TABLE_NUM; ++l) {
            const float r  = res.r[l];
            const int   xs = (int)floorf(cx_lo * r);
            const int   ys = (int)floorf(cy_lo * r);
            const float2* tl = tb2 + l * T_SIZE;
            const int W = WCAP[l], CNT = WCAP[l] * WCAP[l];
            for (int e = tid; e < CNT; e += 256) {
                int yy = e / W, xx = e - yy * W;
                unsigned idx = ((unsigned)(xs + xx) ^
                                ((unsigned)(ys + yy) * PRIME_Y)) & (T_SIZE - 1);
                cstage[CBASE[l] + e] = tl[idx];
            }
        }
        __syncthreads();

        // ---- consume: bilinear from LDS ----
#pragma unroll
        for (int l = 0; l < TABLE_NUM; ++l) {
            const float r   = res.r[l];
            const float xsf = floorf(cx_lo * r);
            const float ysf = floorf(cy_lo * r);
            float px = cxp * r, py = cyp * r;
            float fx0 = floorf(px), fy0 = floorf(py);
            float fx = px - fx0, fy = py - fy0;
            int xi = (int)(fx0 - xsf), yi = (int)(fy0 - ysf);
            const float2* cb = cstage + CBASE[l];
            const int W = WCAP[l];
            float2 f00 = cb[yi * W + xi];
            float2 f10 = cb[yi * W + xi + 1];
            float2 f01 = cb[(yi + 1) * W + xi];
            float2 f11 = cb[(yi + 1) * W + xi + 1];
            float w00 = (1.f - fx) * (1.f - fy);
            float w10 = fx * (1.f - fy);
            float w01 = (1.f - fx) * fy;
            float w11 = fx * fy;
            float e0 = f00.x * w00 + f10.x * w10 + f01.x * w01 + f11.x * w11;
            float e1 = f00.y * w00 + f10.y * w10 + f01.y * w01 + f11.y * w11;
            v2h p; p.x = (_Float16)e0; p.y = (_Float16)e1;
            *reinterpret_cast<v2h*>(&mbuf[wid][lane][2 * l]) = p;
        }

        float bias1v[4], bias2v[4];
#pragma unroll
        for (int nt = 0; nt < 4; ++nt) {
            bias1v[nt] = b1[nt * 16 + arow];
            bias2v[nt] = b2[nt * 16 + arow];
        }
        const float bias3 = (arow < 3) ? b3[arow] : 0.f;

        v8h bf1[4], bf2a[4], bf2b[4];
#pragma unroll
        for (int nt = 0; nt < 4; ++nt) {
            bf1[nt]  = *reinterpret_cast<const v8h*>(&w1T[(nt * 16 + arow) * 32 + kgrp * 8]);
            bf2a[nt] = *reinterpret_cast<const v8h*>(&w2T[(nt * 16 + arow) * 64 + kgrp * 8]);
            bf2b[nt] = *reinterpret_cast<const v8h*>(&w2T[(nt * 16 + arow) * 64 + 32 + kgrp * 8]);
        }
        v8h bf3a = *reinterpret_cast<const v8h*>(&w3T[arow * 64 + kgrp * 8]);
        v8h bf3b = *reinterpret_cast<const v8h*>(&w3T[arow * 64 + 32 + kgrp * 8]);

        // ---- layer 1 ----
        v8h a1[4];
#pragma unroll
        for (int mt = 0; mt < 4; ++mt)
            a1[mt] = *reinterpret_cast<const v8h*>(&mbuf[wid][mt * 16 + arow][kgrp * 8]);

        v4f c1[4][4];
#pragma unroll
        for (int nt = 0; nt < 4; ++nt)
#pragma unroll
            for (int mt = 0; mt < 4; ++mt) {
                v4f c = {0.f, 0.f, 0.f, 0.f};
                c = __builtin_amdgcn_mfma_f32_16x16x32_f16(a1[mt], bf1[nt], c, 0, 0, 0);
#pragma unroll
                for (int e = 0; e < 4; ++e)
                    c1[mt][nt][e] = fmaxf(c[e] + bias1v[nt], 0.f);
            }

#pragma unroll
        for (int mt = 0; mt < 4; ++mt)
#pragma unroll
            for (int nt = 0; nt < 4; ++nt)
#pragma unroll
                for (int e = 0; e < 4; ++e)
                    mbuf[wid][mt * 16 + kgrp * 4 + e][nt * 16 + arow] = (_Float16)c1[mt][nt][e];

        // ---- layer 2 ----
        v8h a2[4][2];
#pragma unroll
        for (int mt = 0; mt < 4; ++mt) {
            a2[mt][0] = *reinterpret_cast<const v8h*>(&mbuf[wid][mt * 16 + arow][kgrp * 8]);
            a2[mt][1] = *reinterpret_cast<const v8h*>(&mbuf[wid][mt * 16 + arow][32 + kgrp * 8]);
        }
        v4f c2[4][4];
#pragma unroll
        for (int nt = 0; nt < 4; ++nt)
#pragma unroll
            for (int mt = 0; mt < 4; ++mt) {
                v4f c = {0.f, 0.f, 0.f, 0.f};
                c = __builtin_amdgcn_mfma_f32_16x16x32_f16(a2[mt][0], bf2a[nt], c, 0, 0, 0);
                c = __builtin_amdgcn_mfma_f32_16x16x32_f16(a2[mt][1], bf2b[nt], c, 0, 0, 0);
#pragma unroll
                for (int e = 0; e < 4; ++e)
                    c2[mt][nt][e] = fmaxf(c[e] + bias2v[nt], 0.f);
            }

#pragma unroll
        for (int mt = 0; mt < 4; ++mt)
#pragma unroll
            for (int nt = 0; nt < 4; ++nt)
#pragma unroll
                for (int e = 0; e < 4; ++e)
                    mbuf[wid][mt * 16 + kgrp * 4 + e][nt * 16 + arow] = (_Float16)c2[mt][nt][e];

        // ---- layer 3 ----
#pragma unroll
        for (int mt = 0; mt < 4; ++mt) {
            v8h a0  = *reinterpret_cast<const v8h*>(&mbuf[wid][mt * 16 + arow][kgrp * 8]);
            v8h a1v = *reinterpret_cast<const v8h*>(&mbuf[wid][mt * 16 + arow][32 + kgrp * 8]);
            v4f c = {0.f, 0.f, 0.f, 0.f};
            c = __builtin_amdgcn_mfma_f32_16x16x32_f16(a0,  bf3a, c, 0, 0, 0);
            c = __builtin_amdgcn_mfma_f32_16x16x32_f16(a1v, bf3b, c, 0, 0, 0);
            if (arow < 3) {
                float4 st;
                st.x = tanhf(c[0] + bias3);
                st.y = tanhf(c[1] + bias3);
                st.z = tanhf(c[2] + bias3);
                st.w = tanhf(c[3] + bias3);
                size_t idx = ((size_t)b * 3 + arow) * N_PIX
                           + (size_t)(i0 + mt) * IMG + j0b + kgrp * 4;
                *reinterpret_cast<float4*>(&out[idx]) = st;
            }
        }
        __syncthreads();   // cstage WAR across reps
    }
}

extern "C" void kernel_launch(void* const* d_in, const int* in_sizes, int n_in,
                              void* d_out, int out_size, void* d_ws, size_t ws_size,
                              hipStream_t stream)
{
    const float* z  = (const float*)d_in[0];
    const float* wt = (const float*)d_in[1];
    const float* bt = (const float*)d_in[2];
    const float* w1 = (const float*)d_in[3];
    const float* b1 = (const float*)d_in[4];
    const float* w2 = (const float*)d_in[5];
    const float* b2 = (const float*)d_in[6];
    const float* w3 = (const float*)d_in[7];
    const float* b3 = (const float*)d_in[8];
    float* out  = (float*)d_out;

    char* ws = (char*)d_ws;
    float*     tabs = (float*)ws;                            // 4 MB
    float*     part = (float*)(ws + (4 << 20));              // 16 MB partials
    _Float16*  w1T  = (_Float16*)(ws + (20 << 20));          // 4 KB
    _Float16*  w2T  = (_Float16*)(ws + (20 << 20) + 4096);   // 8 KB
    _Float16*  w3T  = (_Float16*)(ws + (20 << 20) + 12288);  // 2 KB
    float*     zT   = (float*)(ws + (20 << 20) + 16384);     // 16 KB

    ResArr ra;
    const double growth = std::exp((std::log(256.0) - std::log(16.0)) / 15.0);
    for (int l = 0; l < TABLE_NUM; ++l)
        ra.r[l] = (float)(16.0 * std::pow(growth, (double)l));

    prep_weights<<<1, 256, 0, stream>>>(w1, w2, w3, z, w1T, w2T, w3T, zT);
    gen_partial<<<KCHUNK * (NG4 / 256), 256, 0, stream>>>(zT, wt, part);
    gen_reduce<<<BATCH * NG4 / 256, 256, 0, stream>>>(part, bt, tabs);
    hash_mlp<<<BATCH * (N_PIX / 256), 256, 0, stream>>>(
        tabs, w1T, w2T, w3T, b1, b2, b3, out, ra);
}

// Round 10
// 129.816 us; speedup vs baseline: 3.0390x; 3.0390x over previous
//
#include <hip/hip_runtime.h>
#include <cmath>

#define TABLE_NUM 16
#define T_SIZE    4096
#define Z_DIM     512
#define IMG       256
#define D_TAB     (TABLE_NUM * T_SIZE * 2)       // 131072
#define BATCH     8
#define HID       64
#define N_PIX     (IMG * IMG)                    // 65536
#define PRIME_Y   2654435761u
#define KCHUNK    4
#define KLEN      (Z_DIM / KCHUNK)               // 128
#define NG4       (D_TAB / 4)                    // 32768 float4 col-groups

typedef _Float16 v8h  __attribute__((ext_vector_type(8)));
typedef _Float16 v2h  __attribute__((ext_vector_type(2)));
typedef float    v4f  __attribute__((ext_vector_type(4)));

struct ResArr { float r[TABLE_NUM]; };

// Corner-window caps for a 4(i)x16(j) pixel tile:
//   XW (i/x extent) = floor(3.5*r/256)+3 ; YW (j/y extent) = floor(15.5*r/256)+3
__device__ constexpr int XW[16]    = {3,3,3,3,3,3,3,3,3,4,4,4,5,5,5,6};
__device__ constexpr int YW[16]    = {3,4,4,4,5,5,5,6,7,8,9,10,11,13,15,18};
__device__ constexpr int CBASE[16] = {0,9,21,33,45,60,75,90,108,129,161,197,237,292,357,432};
#define CTOT 540

__device__ __forceinline__ int pkf16(float a, float b) {
    v2h p; p.x = (_Float16)a; p.y = (_Float16)b;
    int r; __builtin_memcpy(&r, &p, 4); return r;
}

// ---------------------------------------------------------------------------
// Kernel 0: weight transpose/cast + z transpose (unchanged from R7).
// ---------------------------------------------------------------------------
__global__ void prep_weights(const float* __restrict__ w1, const float* __restrict__ w2,
                             const float* __restrict__ w3, const float* __restrict__ z,
                             _Float16* __restrict__ w1T, _Float16* __restrict__ w2T,
                             _Float16* __restrict__ w3T, float* __restrict__ zT)
{
    const int t = threadIdx.x;
    for (int i = t; i < HID * 32; i += 256) {
        int n = i >> 5, k = i & 31;
        w1T[i] = (_Float16)w1[k * HID + n];
    }
    for (int i = t; i < HID * HID; i += 256) {
        int n = i >> 6, k = i & 63;
        w2T[i] = (_Float16)w2[k * HID + n];
    }
    for (int i = t; i < 16 * HID; i += 256) {
        int n = i >> 6, k = i & 63;
        w3T[i] = (_Float16)(n < 3 ? w3[k * 3 + n] : 0.f);
    }
    for (int i = t; i < Z_DIM * BATCH; i += 256) {
        int k = i >> 3, b = i & 7;
        zT[i] = z[b * Z_DIM + k];
    }
}

// ---------------------------------------------------------------------------
// Kernel 1a: k-split partial GEMM (unchanged from R7; ~44 us @ 6.4 TB/s).
// ---------------------------------------------------------------------------
__global__ __launch_bounds__(256) void gen_partial(
    const float* __restrict__ zT, const float* __restrict__ w,
    float* __restrict__ part)
{
    const int c  = blockIdx.x >> 7;
    const int g  = (blockIdx.x & 127) * 256 + threadIdx.x;
    const int k0 = c * KLEN;
    const float4* wp = reinterpret_cast<const float4*>(w) + g;

    float4 acc[BATCH];
#pragma unroll
    for (int b = 0; b < BATCH; ++b) acc[b] = make_float4(0.f, 0.f, 0.f, 0.f);

#pragma unroll 8
    for (int kk = 0; kk < KLEN; ++kk) {
        const int k = k0 + kk;
        float4 wv = wp[(size_t)k * NG4];
        const float* zr = zT + k * BATCH;
#pragma unroll
        for (int b = 0; b < BATCH; ++b) {
            float zv = zr[b];
            acc[b].x = fmaf(zv, wv.x, acc[b].x);
            acc[b].y = fmaf(zv, wv.y, acc[b].y);
            acc[b].z = fmaf(zv, wv.z, acc[b].z);
            acc[b].w = fmaf(zv, wv.w, acc[b].w);
        }
    }

    float4* pp = reinterpret_cast<float4*>(part);
#pragma unroll
    for (int b = 0; b < BATCH; ++b)
        pp[((size_t)(c * BATCH + b) << 15) + g] = acc[b];
}

// ---------------------------------------------------------------------------
// Kernel 1b: fold partials + bias (unchanged from R7; ~3.5 us).
// ---------------------------------------------------------------------------
__global__ __launch_bounds__(256) void gen_reduce(
    const float* __restrict__ part, const float* __restrict__ bt,
    float* __restrict__ tabs)
{
    const int i = blockIdx.x * 256 + threadIdx.x;
    const int b = i >> 15, g = i & (NG4 - 1);
    const float4* pp = reinterpret_cast<const float4*>(part);

    float4 s = pp[((size_t)b << 15) + g];
#pragma unroll
    for (int c = 1; c < KCHUNK; ++c) {
        float4 p = pp[((size_t)(c * BATCH + b) << 15) + g];
        s.x += p.x; s.y += p.y; s.z += p.z; s.w += p.w;
    }
    float4 bv = reinterpret_cast<const float4*>(bt)[g];
    s.x += bv.x; s.y += bv.y; s.z += bv.z; s.w += bv.w;
    reinterpret_cast<float4*>(tabs)[((size_t)b << 15) + g] = s;
}

// ---------------------------------------------------------------------------
// Kernel 2 (redesigned): latency-lean hash-grid + MFMA MLP.
//  * block = 256 thr = 4 waves; tile = 4 i-rows x 16 j-cols; wave w -> row w.
//  * lane (g=lane>>4, j=lane&15): computes levels 4g..4g+3 of pixel j ->
//    layer-1 B-fragment (col=j, k=g*8+e) lands in-lane, zero movement.
//  * MLP: weights as A operand, activations as B. D[row=h_out][col=px].
//    Layer transitions via 16 ds_bpermute + 8 selects (no LDS, no barrier):
//    B[kc][d] <- pk[2kc + (g>>1)][d&1] of lane ((2g+(d>>1))&3)*16 + j.
//  * LDS = 540-entry corner pyramid only (4.3 KB); one barrier total.
//  * w2/w3 fragments reloaded at use (L1-hot) to cap VGPR.
// ---------------------------------------------------------------------------
__global__ __launch_bounds__(256) void hash_mlp(
    const float* __restrict__ tabs,
    const _Float16* __restrict__ w1T, const _Float16* __restrict__ w2T,
    const _Float16* __restrict__ w3T,
    const float* __restrict__ b1, const float* __restrict__ b2,
    const float* __restrict__ b3,
    float* __restrict__ out, ResArr res)
{
    __shared__ float2 cstage[CTOT];

    const int tid  = threadIdx.x;
    const int w    = tid >> 6;
    const int lane = tid & 63;
    const int g    = lane >> 4;
    const int arow = lane & 15;
    const int b    = blockIdx.x & 7;          // batch == XCD (round-robin)
    const int tile = blockIdx.x >> 3;
    const int i0b  = (tile >> 4) * 4;         // 64 i-tiles
    const int j0b  = (tile & 15) * 16;        // 16 j-tiles

    const float2* tb2 = reinterpret_cast<const float2*>(tabs + (size_t)b * D_TAB);
    const float cx_lo = ((float)i0b + 0.5f) * (1.0f / IMG);
    const float cy_lo = ((float)j0b + 0.5f) * (1.0f / IMG);

    // ---- stage the 540-entry corner pyramid (single masked pass, 1 barrier)
#pragma unroll
    for (int l = 0; l < TABLE_NUM; ++l) {
        const float r  = res.r[l];
        const int   xs = (int)floorf(cx_lo * r);
        const int   ys = (int)floorf(cy_lo * r);
        const int   Wl = XW[l], CNT = XW[l] * YW[l];
        if (tid < CNT) {
            int yy = tid / Wl, xx = tid - yy * Wl;        // compile-time div
            unsigned idx = ((unsigned)(xs + xx) ^
                            ((unsigned)(ys + yy) * PRIME_Y)) & (T_SIZE - 1);
            cstage[CBASE[l] + tid] = tb2[l * T_SIZE + idx];
        }
    }
    __syncthreads();

    const int ii = i0b + w;
    const int jj = j0b + arow;
    const float cxp = ((float)ii + 0.5f) * (1.0f / IMG);
    const float cyp = ((float)jj + 0.5f) * (1.0f / IMG);

    // ---- features: lane computes its 4 levels (4g+fi) of pixel jj ----
    v8h bfeat;
#pragma unroll
    for (int fi = 0; fi < 4; ++fi) {
        const float r  = g == 0 ? res.r[fi]     : g == 1 ? res.r[4 + fi]
                       : g == 2 ? res.r[8 + fi] : res.r[12 + fi];
        const int  Wl  = g == 0 ? XW[fi]        : g == 1 ? XW[4 + fi]
                       : g == 2 ? XW[8 + fi]    : XW[12 + fi];
        const int  bas = g == 0 ? CBASE[fi]     : g == 1 ? CBASE[4 + fi]
                       : g == 2 ? CBASE[8 + fi] : CBASE[12 + fi];
        float xsf = floorf(cx_lo * r), ysf = floorf(cy_lo * r);
        float px = cxp * r, py = cyp * r;
        float fx0 = floorf(px), fy0 = floorf(py);
        float fx = px - fx0, fy = py - fy0;
        int xi = (int)(fx0 - xsf), yi = (int)(fy0 - ysf);
        const float2* cb = cstage + bas;
        float2 f00 = cb[yi * Wl + xi];
        float2 f10 = cb[yi * Wl + xi + 1];
        float2 f01 = cb[(yi + 1) * Wl + xi];
        float2 f11 = cb[(yi + 1) * Wl + xi + 1];
        float w00 = (1.f - fx) * (1.f - fy);
        float w10 = fx * (1.f - fy);
        float w01 = (1.f - fx) * fy;
        float w11 = fx * fy;
        float e0 = f00.x * w00 + f10.x * w10 + f01.x * w01 + f11.x * w11;
        float e1 = f00.y * w00 + f10.y * w10 + f01.y * w01 + f11.y * w11;
        bfeat[2 * fi]     = (_Float16)e0;
        bfeat[2 * fi + 1] = (_Float16)e1;
    }

    // bpermute lane indices (byte addresses) for the two k-sub-slices
    const int idx0 = ((((2 * g + 0) & 3) << 4) | arow) << 2;
    const int idx1 = ((((2 * g + 1) & 3) << 4) | arow) << 2;
    const bool ghi = (g >= 2);

    // ---- layer 1: D[h=mt*16+g*4+e][px=arow] = W1 x feat, bias+relu ----
    v4f c1[4];
#pragma unroll
    for (int mt = 0; mt < 4; ++mt) {
        v8h wa = *reinterpret_cast<const v8h*>(&w1T[(mt * 16 + arow) * 32 + g * 8]);
        v4f c = {0.f, 0.f, 0.f, 0.f};
        c = __builtin_amdgcn_mfma_f32_16x16x32_f16(wa, bfeat, c, 0, 0, 0);
        float4 bv = *reinterpret_cast<const float4*>(&b1[mt * 16 + g * 4]);
        c1[mt][0] = fmaxf(c[0] + bv.x, 0.f);
        c1[mt][1] = fmaxf(c[1] + bv.y, 0.f);
        c1[mt][2] = fmaxf(c[2] + bv.z, 0.f);
        c1[mt][3] = fmaxf(c[3] + bv.w, 0.f);
    }

    // ---- transition 1->2: pack f16 pairs, redistribute via bpermute ----
    int pk1[4][2];
#pragma unroll
    for (int mt = 0; mt < 4; ++mt) {
        pk1[mt][0] = pkf16(c1[mt][0], c1[mt][1]);
        pk1[mt][1] = pkf16(c1[mt][2], c1[mt][3]);
    }
    v8h bB2[2];
#pragma unroll
    for (int kc = 0; kc < 2; ++kc) {
        int t[4];
#pragma unroll
        for (int d = 0; d < 4; ++d) {
            int idx = (d >> 1) ? idx1 : idx0;
            int lo = __builtin_amdgcn_ds_bpermute(idx, pk1[2 * kc][d & 1]);
            int hi = __builtin_amdgcn_ds_bpermute(idx, pk1[2 * kc + 1][d & 1]);
            t[d] = ghi ? hi : lo;
        }
        __builtin_memcpy(&bB2[kc], t, 16);
    }

    // ---- layer 2: K=64, weights reloaded at use ----
    v4f c2[4];
#pragma unroll
    for (int mt = 0; mt < 4; ++mt) {
        v8h wa0 = *reinterpret_cast<const v8h*>(&w2T[(mt * 16 + arow) * 64 + g * 8]);
        v8h wa1 = *reinterpret_cast<const v8h*>(&w2T[(mt * 16 + arow) * 64 + 32 + g * 8]);
        v4f c = {0.f, 0.f, 0.f, 0.f};
        c = __builtin_amdgcn_mfma_f32_16x16x32_f16(wa0, bB2[0], c, 0, 0, 0);
        c = __builtin_amdgcn_mfma_f32_16x16x32_f16(wa1, bB2[1], c, 0, 0, 0);
        float4 bv = *reinterpret_cast<const float4*>(&b2[mt * 16 + g * 4]);
        c2[mt][0] = fmaxf(c[0] + bv.x, 0.f);
        c2[mt][1] = fmaxf(c[1] + bv.y, 0.f);
        c2[mt][2] = fmaxf(c[2] + bv.z, 0.f);
        c2[mt][3] = fmaxf(c[3] + bv.w, 0.f);
    }

    // ---- transition 2->3 ----
    int pk2[4][2];
#pragma unroll
    for (int mt = 0; mt < 4; ++mt) {
        pk2[mt][0] = pkf16(c2[mt][0], c2[mt][1]);
        pk2[mt][1] = pkf16(c2[mt][2], c2[mt][3]);
    }
    v8h bB3[2];
#pragma unroll
    for (int kc = 0; kc < 2; ++kc) {
        int t[4];
#pragma unroll
        for (int d = 0; d < 4; ++d) {
            int idx = (d >> 1) ? idx1 : idx0;
            int lo = __builtin_amdgcn_ds_bpermute(idx, pk2[2 * kc][d & 1]);
            int hi = __builtin_amdgcn_ds_bpermute(idx, pk2[2 * kc + 1][d & 1]);
            t[d] = ghi ? hi : lo;
        }
        __builtin_memcpy(&bB3[kc], t, 16);
    }

    // ---- layer 3: 64 -> 3 (rows 0..2 of padded 16), tanh, store ----
    v8h w3a = *reinterpret_cast<const v8h*>(&w3T[arow * 64 + g * 8]);
    v8h w3b = *reinterpret_cast<const v8h*>(&w3T[arow * 64 + 32 + g * 8]);
    v4f c3 = {0.f, 0.f, 0.f, 0.f};
    c3 = __builtin_amdgcn_mfma_f32_16x16x32_f16(w3a, bB3[0], c3, 0, 0, 0);
    c3 = __builtin_amdgcn_mfma_f32_16x16x32_f16(w3b, bB3[1], c3, 0, 0, 0);

    if (g == 0) {                       // lanes 0..15 hold ch=e of pixel arow
#pragma unroll
        for (int e = 0; e < 3; ++e) {
            float o = tanhf(c3[e] + b3[e]);
            out[((size_t)(b * 3 + e)) * N_PIX + (size_t)ii * IMG + jj] = o;
        }
    }
}

extern "C" void kernel_launch(void* const* d_in, const int* in_sizes, int n_in,
                              void* d_out, int out_size, void* d_ws, size_t ws_size,
                              hipStream_t stream)
{
    const float* z  = (const float*)d_in[0];
    const float* wt = (const float*)d_in[1];
    const float* bt = (const float*)d_in[2];
    const float* w1 = (const float*)d_in[3];
    const float* b1 = (const float*)d_in[4];
    const float* w2 = (const float*)d_in[5];
    const float* b2 = (const float*)d_in[6];
    const float* w3 = (const float*)d_in[7];
    const float* b3 = (const float*)d_in[8];
    float* out  = (float*)d_out;

    char* ws = (char*)d_ws;
    float*     tabs = (float*)ws;                            // 4 MB
    float*     part = (float*)(ws + (4 << 20));              // 16 MB partials
    _Float16*  w1T  = (_Float16*)(ws + (20 << 20));          // 4 KB
    _Float16*  w2T  = (_Float16*)(ws + (20 << 20) + 4096);   // 8 KB
    _Float16*  w3T  = (_Float16*)(ws + (20 << 20) + 12288);  // 2 KB
    float*     zT   = (float*)(ws + (20 << 20) + 16384);     // 16 KB

    ResArr ra;
    const double growth = std::exp((std::log(256.0) - std::log(16.0)) / 15.0);
    for (int l = 0; l < TABLE_NUM; ++l)
        ra.r[l] = (float)(16.0 * std::pow(growth, (double)l));

    prep_weights<<<1, 256, 0, stream>>>(w1, w2, w3, z, w1T, w2T, w3T, zT);
    gen_partial<<<KCHUNK * (NG4 / 256), 256, 0, stream>>>(zT, wt, part);
    gen_reduce<<<BATCH * NG4 / 256, 256, 0, stream>>>(part, bt, tabs);
    // 4x16 pixel tile per block: 64*16 = 1024 tiles... (65536/64)=1024 tiles x 8
    hash_mlp<<<BATCH * (N_PIX / 64), 256, 0, stream>>>(
        tabs, w1T, w2T, w3T, b1, b2, b3, out, ra);
}

// Round 12
// 98.397 us; speedup vs baseline: 4.0094x; 1.3193x over previous
//
#include <hip/hip_runtime.h>
#include <cmath>

#define TABLE_NUM 16
#define T_SIZE    4096
#define Z_DIM     512
#define IMG       256
#define D_TAB     (TABLE_NUM * T_SIZE * 2)       // 131072
#define BATCH     8
#define HID       64
#define N_PIX     (IMG * IMG)                    // 65536
#define PRIME_Y   2654435761u
#define KCHUNK    4
#define KLEN      (Z_DIM / KCHUNK)               // 128
#define NG4       (D_TAB / 4)                    // 32768 float4 col-groups

typedef _Float16 v8h  __attribute__((ext_vector_type(8)));
typedef _Float16 v2h  __attribute__((ext_vector_type(2)));
typedef float    v4f  __attribute__((ext_vector_type(4)));

struct ResArr { float r[TABLE_NUM]; };

// ---------------------------------------------------------------------------
// Kernel 0: weight transpose/cast + z transpose (unchanged from R7).
// ---------------------------------------------------------------------------
__global__ void prep_weights(const float* __restrict__ w1, const float* __restrict__ w2,
                             const float* __restrict__ w3, const float* __restrict__ z,
                             _Float16* __restrict__ w1T, _Float16* __restrict__ w2T,
                             _Float16* __restrict__ w3T, float* __restrict__ zT)
{
    const int t = threadIdx.x;
    for (int i = t; i < HID * 32; i += 256) {
        int n = i >> 5, k = i & 31;
        w1T[i] = (_Float16)w1[k * HID + n];
    }
    for (int i = t; i < HID * HID; i += 256) {
        int n = i >> 6, k = i & 63;
        w2T[i] = (_Float16)w2[k * HID + n];
    }
    for (int i = t; i < 16 * HID; i += 256) {
        int n = i >> 6, k = i & 63;
        w3T[i] = (_Float16)(n < 3 ? w3[k * 3 + n] : 0.f);
    }
    for (int i = t; i < Z_DIM * BATCH; i += 256) {
        int k = i >> 3, b = i & 7;
        zT[i] = z[b * Z_DIM + k];
    }
}

// ---------------------------------------------------------------------------
// Kernel 1a: k-split partial GEMM (unchanged from R7; ~44 us @ 6.4 TB/s).
// ---------------------------------------------------------------------------
__global__ __launch_bounds__(256) void gen_partial(
    const float* __restrict__ zT, const float* __restrict__ w,
    float* __restrict__ part)
{
    const int c  = blockIdx.x >> 7;
    const int g  = (blockIdx.x & 127) * 256 + threadIdx.x;
    const int k0 = c * KLEN;
    const float4* wp = reinterpret_cast<const float4*>(w) + g;

    float4 acc[BATCH];
#pragma unroll
    for (int b = 0; b < BATCH; ++b) acc[b] = make_float4(0.f, 0.f, 0.f, 0.f);

#pragma unroll 8
    for (int kk = 0; kk < KLEN; ++kk) {
        const int k = k0 + kk;
        float4 wv = wp[(size_t)k * NG4];
        const float* zr = zT + k * BATCH;
#pragma unroll
        for (int b = 0; b < BATCH; ++b) {
            float zv = zr[b];
            acc[b].x = fmaf(zv, wv.x, acc[b].x);
            acc[b].y = fmaf(zv, wv.y, acc[b].y);
            acc[b].z = fmaf(zv, wv.z, acc[b].z);
            acc[b].w = fmaf(zv, wv.w, acc[b].w);
        }
    }

    float4* pp = reinterpret_cast<float4*>(part);
#pragma unroll
    for (int b = 0; b < BATCH; ++b)
        pp[((size_t)(c * BATCH + b) << 15) + g] = acc[b];
}

// ---------------------------------------------------------------------------
// Kernel 1b: fold partials + bias (unchanged from R7; ~3.5 us).
// ---------------------------------------------------------------------------
__global__ __launch_bounds__(256) void gen_reduce(
    const float* __restrict__ part, const float* __restrict__ bt,
    float* __restrict__ tabs)
{
    const int i = blockIdx.x * 256 + threadIdx.x;
    const int b = i >> 15, g = i & (NG4 - 1);
    const float4* pp = reinterpret_cast<const float4*>(part);

    float4 s = pp[((size_t)b << 15) + g];
#pragma unroll
    for (int c = 1; c < KCHUNK; ++c) {
        float4 p = pp[((size_t)(c * BATCH + b) << 15) + g];
        s.x += p.x; s.y += p.y; s.z += p.z; s.w += p.w;
    }
    float4 bv = reinterpret_cast<const float4*>(bt)[g];
    s.x += bv.x; s.y += bv.y; s.z += bv.z; s.w += bv.w;
    reinterpret_cast<float4*>(tabs)[((size_t)b << 15) + g] = s;
}

// ---------------------------------------------------------------------------
// Kernel 2: EXACT R4 hash_mlp structure (proven correct 5 rounds) with ONE
// correctness-neutral change: weight B-fragments reloaded from L1 inside the
// nt loops instead of hoisted (-56 VGPR -> target <=128 -> 4 waves/SIMD
// naturally, no forced launch_bounds). The LDS read/write sequence is
// bit-identical to R4 — only global-load scheduling differs.
// ---------------------------------------------------------------------------
__global__ __launch_bounds__(256) void hash_mlp(
    const float* __restrict__ tabs,
    const _Float16* __restrict__ w1T, const _Float16* __restrict__ w2T,
    const _Float16* __restrict__ w3T,
    const float* __restrict__ b1, const float* __restrict__ b2,
    const float* __restrict__ b3,
    float* __restrict__ out, ResArr res)
{
    __shared__ _Float16 mbuf[4][64][72];
    const int tid  = threadIdx.x;
    const int wid  = tid >> 6;
    const int lane = tid & 63;
    const int b    = blockIdx.x & 7;          // batch == XCD (round-robin)
    const int tile = blockIdx.x >> 3;         // 16x16 pixel block
    const int i0   = (tile >> 4) * 16 + wid * 4;
    const int j0   = (tile & 15) * 16;

    const int di = lane >> 4, dj = lane & 15;
    const float cx = ((float)(i0 + di) + 0.5f) * (1.0f / IMG);
    const float cy = ((float)(j0 + dj) + 0.5f) * (1.0f / IMG);
    const float2* tb2 = reinterpret_cast<const float2*>(tabs + (size_t)b * D_TAB);

    // ---- hash-grid features: direct global gathers, f16 pairs to LDS ----
#pragma unroll 4
    for (int l = 0; l < TABLE_NUM; ++l) {
        float r  = res.r[l];
        float px = cx * r, py = cy * r;
        float fx0 = floorf(px), fy0 = floorf(py);
        float fx = px - fx0, fy = py - fy0;
        unsigned x0 = (unsigned)(int)fx0, y0 = (unsigned)(int)fy0;
        unsigned hy0 = y0 * PRIME_Y, hy1 = (y0 + 1u) * PRIME_Y;
        unsigned i00 = (x0 ^ hy0) & (T_SIZE - 1);
        unsigned i10 = ((x0 + 1u) ^ hy0) & (T_SIZE - 1);
        unsigned i01 = (x0 ^ hy1) & (T_SIZE - 1);
        unsigned i11 = ((x0 + 1u) ^ hy1) & (T_SIZE - 1);
        const float2* tl = tb2 + l * T_SIZE;
        float2 f00 = tl[i00], f10 = tl[i10], f01 = tl[i01], f11 = tl[i11];
        float w00 = (1.f - fx) * (1.f - fy);
        float w10 = fx * (1.f - fy);
        float w01 = (1.f - fx) * fy;
        float w11 = fx * fy;
        float e0 = f00.x * w00 + f10.x * w10 + f01.x * w01 + f11.x * w11;
        float e1 = f00.y * w00 + f10.y * w10 + f01.y * w01 + f11.y * w11;
        v2h p; p.x = (_Float16)e0; p.y = (_Float16)e1;
        *reinterpret_cast<v2h*>(&mbuf[wid][lane][2 * l]) = p;
    }

    const int arow = lane & 15;        // A row / B col / C col
    const int kgrp = lane >> 4;        // k-group

    float bias1v[4], bias2v[4];
#pragma unroll
    for (int nt = 0; nt < 4; ++nt) {
        bias1v[nt] = b1[nt * 16 + arow];
        bias2v[nt] = b2[nt * 16 + arow];
    }
    const float bias3 = (arow < 3) ? b3[arow] : 0.f;

    // ---- layer 1: 32 -> 64 ----
    v8h a1[4];
#pragma unroll
    for (int mt = 0; mt < 4; ++mt)
        a1[mt] = *reinterpret_cast<const v8h*>(&mbuf[wid][mt * 16 + arow][kgrp * 8]);

    v4f c1[4][4];
#pragma unroll
    for (int nt = 0; nt < 4; ++nt) {
        v8h bf1 = *reinterpret_cast<const v8h*>(&w1T[(nt * 16 + arow) * 32 + kgrp * 8]);
#pragma unroll
        for (int mt = 0; mt < 4; ++mt) {
            v4f c = {0.f, 0.f, 0.f, 0.f};
            c = __builtin_amdgcn_mfma_f32_16x16x32_f16(a1[mt], bf1, c, 0, 0, 0);
#pragma unroll
            for (int e = 0; e < 4; ++e)
                c1[mt][nt][e] = fmaxf(c[e] + bias1v[nt], 0.f);
        }
    }

#pragma unroll
    for (int mt = 0; mt < 4; ++mt)
#pragma unroll
        for (int nt = 0; nt < 4; ++nt)
#pragma unroll
            for (int e = 0; e < 4; ++e)
                mbuf[wid][mt * 16 + kgrp * 4 + e][nt * 16 + arow] = (_Float16)c1[mt][nt][e];

    // ---- layer 2: 64 -> 64 ----
    v8h a2[4][2];
#pragma unroll
    for (int mt = 0; mt < 4; ++mt) {
        a2[mt][0] = *reinterpret_cast<const v8h*>(&mbuf[wid][mt * 16 + arow][kgrp * 8]);
        a2[mt][1] = *reinterpret_cast<const v8h*>(&mbuf[wid][mt * 16 + arow][32 + kgrp * 8]);
    }
    v4f c2[4][4];
#pragma unroll
    for (int nt = 0; nt < 4; ++nt) {
        v8h bf2a = *reinterpret_cast<const v8h*>(&w2T[(nt * 16 + arow) * 64 + kgrp * 8]);
        v8h bf2b = *reinterpret_cast<const v8h*>(&w2T[(nt * 16 + arow) * 64 + 32 + kgrp * 8]);
#pragma unroll
        for (int mt = 0; mt < 4; ++mt) {
            v4f c = {0.f, 0.f, 0.f, 0.f};
            c = __builtin_amdgcn_mfma_f32_16x16x32_f16(a2[mt][0], bf2a, c, 0, 0, 0);
            c = __builtin_amdgcn_mfma_f32_16x16x32_f16(a2[mt][1], bf2b, c, 0, 0, 0);
#pragma unroll
            for (int e = 0; e < 4; ++e)
                c2[mt][nt][e] = fmaxf(c[e] + bias2v[nt], 0.f);
        }
    }

#pragma unroll
    for (int mt = 0; mt < 4; ++mt)
#pragma unroll
        for (int nt = 0; nt < 4; ++nt)
#pragma unroll
            for (int e = 0; e < 4; ++e)
                mbuf[wid][mt * 16 + kgrp * 4 + e][nt * 16 + arow] = (_Float16)c2[mt][nt][e];

    // ---- layer 3: 64 -> 3 (padded 16), tanh, coalesced row stores ----
#pragma unroll
    for (int mt = 0; mt < 4; ++mt) {
        v8h bf3a = *reinterpret_cast<const v8h*>(&w3T[arow * 64 + kgrp * 8]);
        v8h bf3b = *reinterpret_cast<const v8h*>(&w3T[arow * 64 + 32 + kgrp * 8]);
        v8h a0  = *reinterpret_cast<const v8h*>(&mbuf[wid][mt * 16 + arow][kgrp * 8]);
        v8h a1v = *reinterpret_cast<const v8h*>(&mbuf[wid][mt * 16 + arow][32 + kgrp * 8]);
        v4f c = {0.f, 0.f, 0.f, 0.f};
        c = __builtin_amdgcn_mfma_f32_16x16x32_f16(a0,  bf3a, c, 0, 0, 0);
        c = __builtin_amdgcn_mfma_f32_16x16x32_f16(a1v, bf3b, c, 0, 0, 0);
        if (arow < 3) {
            float4 st;
            st.x = tanhf(c[0] + bias3);
            st.y = tanhf(c[1] + bias3);
            st.z = tanhf(c[2] + bias3);
            st.w = tanhf(c[3] + bias3);
            size_t idx = ((size_t)b * 3 + arow) * N_PIX
                       + (size_t)(i0 + mt) * IMG + j0 + kgrp * 4;
            *reinterpret_cast<float4*>(&out[idx]) = st;
        }
    }
}

extern "C" void kernel_launch(void* const* d_in, const int* in_sizes, int n_in,
                              void* d_out, int out_size, void* d_ws, size_t ws_size,
                              hipStream_t stream)
{
    const float* z  = (const float*)d_in[0];
    const float* wt = (const float*)d_in[1];
    const float* bt = (const float*)d_in[2];
    const float* w1 = (const float*)d_in[3];
    const float* b1 = (const float*)d_in[4];
    const float* w2 = (const float*)d_in[5];
    const float* b2 = (const float*)d_in[6];
    const float* w3 = (const float*)d_in[7];
    const float* b3 = (const float*)d_in[8];
    float* out  = (float*)d_out;

    char* ws = (char*)d_ws;
    float*     tabs = (float*)ws;                            // 4 MB
    float*     part = (float*)(ws + (4 << 20));              // 16 MB partials
    _Float16*  w1T  = (_Float16*)(ws + (20 << 20));          // 4 KB
    _Float16*  w2T  = (_Float16*)(ws + (20 << 20) + 4096);   // 8 KB
    _Float16*  w3T  = (_Float16*)(ws + (20 << 20) + 12288);  // 2 KB
    float*     zT   = (float*)(ws + (20 << 20) + 16384);     // 16 KB

    ResArr ra;
    const double growth = std::exp((std::log(256.0) - std::log(16.0)) / 15.0);
    for (int l = 0; l < TABLE_NUM; ++l)
        ra.r[l] = (float)(16.0 * std::pow(growth, (double)l));

    prep_weights<<<1, 256, 0, stream>>>(w1, w2, w3, z, w1T, w2T, w3T, zT);
    gen_partial<<<KCHUNK * (NG4 / 256), 256, 0, stream>>>(zT, wt, part);
    gen_reduce<<<BATCH * NG4 / 256, 256, 0, stream>>>(part, bt, tabs);
    hash_mlp<<<BATCH * (N_PIX / 256), 256, 0, stream>>>(
        tabs, w1T, w2T, w3T, b1, b2, b3, out, ra);
}